// Round 6
// baseline (262.229 us; speedup 1.0000x reference)
//
#include <hip/hip_runtime.h>
#include <math.h>

#define Bn 32
#define Cn 256
#define Hn 64
#define Wn 64
#define HWn (Hn * Wn)          /* 4096 */
#define CHWn (Cn * HWn)        /* 1048576 */
#define NBLK 1024              /* 4 blocks/CU on 256 CUs -> all co-resident */
#define RPB 2                  /* (b,h) rows per block */

typedef float f32x4 __attribute__((ext_vector_type(4)));

// ---------------------------------------------------------------------------
// Single persistent kernel:
//   phase 1: each block pools its RPB rows (channel-blocked ascending order)
//   grid barrier (agent-scope atomics; counter zeroed by hipMemsetAsync)
//   phase 2: conv(7x7)+sigmoid gate for the SAME rows, then out = gate * X,
//            consuming channels in REVERSE order so the most-recently-pooled
//            X lines are re-read from this XCD's L2 before eviction.
// nt-stores on out keep the write stream from allocating over X in L2.
// Co-residency arithmetic: 1024 blocks @ __launch_bounds__(256,4):
//   4 blocks/CU, 16 waves/CU, LDS ~8.8KB/block, VGPR <= 128. All resident.
// ---------------------------------------------------------------------------
__global__ __launch_bounds__(256, 4) void fused_all(const float* __restrict__ X,
                                                    const float* __restrict__ wgt,   // 98 (OIHW)
                                                    const float* __restrict__ bias,  // 1
                                                    float* __restrict__ out,
                                                    float* __restrict__ maxp,
                                                    float* __restrict__ avgp,
                                                    unsigned* __restrict__ bar) {
    const int tid = threadIdx.x;
    const int w4  = tid & 15;    // float4 column within a row (0..15)
    const int c0  = tid >> 4;    // channel sub-index (0..15)

    __shared__ f32x4 smax[256];
    __shared__ f32x4 ssum[256];
    __shared__ float ws[98];
    __shared__ float part[4][64];
    __shared__ float gate[64];

    if (tid < 98) ws[tid] = wgt[tid];   // consumed after the barrier

    const int gr0 = blockIdx.x * RPB;

    // ---------------- phase 1: pool ----------------
    #pragma unroll
    for (int rr = 0; rr < RPB; ++rr) {
        const int gr = gr0 + rr;
        const int b = gr >> 6;
        const int h = gr & 63;
        const f32x4* Xb = (const f32x4*)(X + (size_t)b * CHWn + (size_t)h * Wn) + w4;

        f32x4 mx = { -INFINITY, -INFINITY, -INFINITY, -INFINITY };
        f32x4 sm = { 0.f, 0.f, 0.f, 0.f };
        #pragma unroll
        for (int kk = 0; kk < 16; ++kk) {       // ascending channel blocks
            const int c = kk * 16 + c0;
            f32x4 v = Xb[(size_t)c * (HWn / 4)];
            mx.x = fmaxf(mx.x, v.x); mx.y = fmaxf(mx.y, v.y);
            mx.z = fmaxf(mx.z, v.z); mx.w = fmaxf(mx.w, v.w);
            sm += v;
        }

        if (rr) __syncthreads();          // previous row's readers done
        smax[tid] = mx;
        ssum[tid] = sm;
        __syncthreads();

        #pragma unroll
        for (int s = 128; s >= 16; s >>= 1) {   // reduce across c0 (stride-16 groups)
            if (tid < s) {
                f32x4 a = smax[tid], c = smax[tid + s];
                a.x = fmaxf(a.x, c.x); a.y = fmaxf(a.y, c.y);
                a.z = fmaxf(a.z, c.z); a.w = fmaxf(a.w, c.w);
                smax[tid] = a;
                ssum[tid] += ssum[tid + s];
            }
            __syncthreads();
        }

        if (tid < 16) {
            const int o = gr * 16 + tid;        // == b*(HWn/4) + h*16 + tid
            ((f32x4*)maxp)[o] = smax[tid];
            ((f32x4*)avgp)[o] = ssum[tid] * (1.0f / (float)Cn);
        }
    }

    // ---------------- grid barrier ----------------
    __syncthreads();
    if (tid == 0) {
        __threadfence();   // make pooled rows visible device-wide
        __hip_atomic_fetch_add(bar, 1u, __ATOMIC_ACQ_REL, __HIP_MEMORY_SCOPE_AGENT);
        while (__hip_atomic_load(bar, __ATOMIC_ACQUIRE, __HIP_MEMORY_SCOPE_AGENT) < NBLK)
            __builtin_amdgcn_s_sleep(2);
    }
    __syncthreads();
    __threadfence();

    // ---------------- phase 2: conv + gate + scale ----------------
    #pragma unroll
    for (int rr = 0; rr < RPB; ++rr) {
        const int gr = gr0 + rr;
        const int b = gr >> 6;
        const int h = gr & 63;

        // conv partials: wave g handles kernel rows {g, g+4}; pixel x = tid & 63
        {
            const int x = tid & 63;
            const int g = tid >> 6;
            const float* mp = maxp + b * HWn;
            const float* ap = avgp + b * HWn;
            float acc = 0.f;
            #pragma unroll
            for (int ii = 0; ii < 2; ++ii) {
                const int i = g + ii * 4;       // rows 0..6 (g=3,ii=1 -> 7: skip)
                if (i > 6) continue;
                const int yy = h + i - 3;
                if (yy < 0 || yy >= Hn) continue;
                #pragma unroll
                for (int j = 0; j < 7; ++j) {
                    const int xx = x + j - 3;
                    if (xx < 0 || xx >= Wn) continue;
                    const int o = yy * Wn + xx;
                    acc += ws[i * 7 + j] * mp[o] + ws[49 + i * 7 + j] * ap[o];
                }
            }
            part[g][x] = acc;
        }
        __syncthreads();

        if (tid < 64) {
            const float acc = bias[0] + part[0][tid] + part[1][tid] + part[2][tid] + part[3][tid];
            gate[tid] = 1.0f / (1.0f + expf(-acc));
        }
        __syncthreads();

        const f32x4 g4 = ((const f32x4*)gate)[w4];
        const f32x4* X4 = (const f32x4*)(X   + (size_t)b * CHWn + (size_t)h * Wn) + w4;
        f32x4*       O4 = (f32x4*)      (out + (size_t)b * CHWn + (size_t)h * Wn) + w4;

        #pragma unroll
        for (int k = 15; k >= 0; --k) {         // reverse: freshest L2 lines first
            const int c = k * 16 + c0;
            const size_t off = (size_t)c * (HWn / 4);
            f32x4 v = X4[off];
            v *= g4;
            __builtin_nontemporal_store(v, O4 + off);
        }
        // next iteration's part[] write is ordered after this iteration's
        // gate reads by the __syncthreads() pair above.
    }
}

extern "C" void kernel_launch(void* const* d_in, const int* in_sizes, int n_in,
                              void* d_out, int out_size, void* d_ws, size_t ws_size,
                              hipStream_t stream) {
    const float* X      = (const float*)d_in[0];
    const float* conv_w = (const float*)d_in[1];
    const float* conv_b = (const float*)d_in[2];
    float* out = (float*)d_out;

    // workspace layout: maxp (512 KiB) | avgp (512 KiB) | barrier counter
    float* maxp = (float*)d_ws;
    float* avgp = maxp + Bn * HWn;
    unsigned* bar = (unsigned*)((char*)d_ws + (1u << 20));

    hipMemsetAsync(bar, 0, sizeof(unsigned), stream);   // graph-capturable node
    fused_all<<<NBLK, 256, 0, stream>>>(X, conv_w, conv_b, out, maxp, avgp, bar);
}

// Round 7
// 69.283 us; speedup vs baseline: 3.7849x; 3.7849x over previous
//
#include <hip/hip_runtime.h>
#include <math.h>

#define Bn 32
#define Cn 256
#define Hn 64
#define Wn 64
#define HWn (Hn * Wn)          /* 4096 */
#define CHWn (Cn * HWn)        /* 1048576 */

typedef float f32x4 __attribute__((ext_vector_type(4)));

// ---------------------------------------------------------------------------
// Kernel 1: channel-wise max & mean pooling. (round-5 version, unchanged)
// One block per (b, h) row. 256 threads = 16 channel-groups x 16 float4 cols.
// ---------------------------------------------------------------------------
__global__ __launch_bounds__(256) void pool_kernel(const float* __restrict__ X,
                                                   float* __restrict__ maxp,
                                                   float* __restrict__ avgp) {
    const int tid   = threadIdx.x;
    const int w4    = tid & 15;    // float4 column within the row (0..15)
    const int c_sub = tid >> 4;    // channel group (0..15)
    const int b     = blockIdx.x >> 6;
    const int h     = blockIdx.x & 63;

    const f32x4* Xb = (const f32x4*)(X + (size_t)b * CHWn + (size_t)h * Wn) + w4;

    f32x4 mx = { -INFINITY, -INFINITY, -INFINITY, -INFINITY };
    f32x4 sm = { 0.f, 0.f, 0.f, 0.f };
    #pragma unroll
    for (int k = 0; k < 16; ++k) {
        const int c = c_sub * 16 + k;
        f32x4 v = Xb[(size_t)c * (HWn / 4)];
        mx.x = fmaxf(mx.x, v.x); mx.y = fmaxf(mx.y, v.y);
        mx.z = fmaxf(mx.z, v.z); mx.w = fmaxf(mx.w, v.w);
        sm += v;
    }

    __shared__ f32x4 smax[256];
    __shared__ f32x4 ssum[256];
    smax[tid] = mx;
    ssum[tid] = sm;
    __syncthreads();

    #pragma unroll
    for (int s = 128; s >= 16; s >>= 1) {
        if (tid < s) {
            f32x4 a = smax[tid], c = smax[tid + s];
            a.x = fmaxf(a.x, c.x); a.y = fmaxf(a.y, c.y);
            a.z = fmaxf(a.z, c.z); a.w = fmaxf(a.w, c.w);
            smax[tid] = a;
            ssum[tid] += ssum[tid + s];
        }
        __syncthreads();
    }

    if (tid < 16) {
        f32x4 m = smax[tid];
        f32x4 a = ssum[tid] * (1.0f / (float)Cn);
        const int o = b * (HWn / 4) + h * 16 + tid;
        ((f32x4*)maxp)[o] = m;
        ((f32x4*)avgp)[o] = a;
    }
}

// ---------------------------------------------------------------------------
// Kernel 2 (fused): 7x7 conv + bias + sigmoid -> gate (LDS), then
// out[b,c,h,:] = gate[h,:] * X[b,c,h,:] for all 256 channels.
// One block per (b, h) row; conv split across the 4 waves.
// Scale loop restructured into batches of 4: 4 loads issued back-to-back
// (guaranteed MLP), then 4 mul+nt-stores, so the next batch's loads overlap
// this batch's store drain.
// ---------------------------------------------------------------------------
__global__ __launch_bounds__(256) void conv_scale_kernel(const float* __restrict__ X,
                                                         const float* __restrict__ maxp,
                                                         const float* __restrict__ avgp,
                                                         const float* __restrict__ wgt,  // 98 (OIHW)
                                                         const float* __restrict__ bias, // 1
                                                         float* __restrict__ out) {
    __shared__ float ws[98];
    __shared__ float part[4][64];
    __shared__ float gate[64];

    const int tid = threadIdx.x;
    const int b = blockIdx.x >> 6;
    const int h = blockIdx.x & 63;

    if (tid < 98) ws[tid] = wgt[tid];
    __syncthreads();

    // conv partials: wave g handles kernel rows {g, g+4}; pixel x = tid & 63
    {
        const int x = tid & 63;
        const int g = tid >> 6;
        const float* mp = maxp + b * HWn;
        const float* ap = avgp + b * HWn;
        float acc = 0.f;
        #pragma unroll
        for (int ii = 0; ii < 2; ++ii) {
            const int i = g + ii * 4;          // rows 0..6 (g=3,ii=1 -> 7: skip)
            if (i > 6) continue;
            const int yy = h + i - 3;
            if (yy < 0 || yy >= Hn) continue;
            #pragma unroll
            for (int j = 0; j < 7; ++j) {
                const int xx = x + j - 3;
                if (xx < 0 || xx >= Wn) continue;
                const int o = yy * Wn + xx;
                acc += ws[i * 7 + j] * mp[o] + ws[49 + i * 7 + j] * ap[o];
            }
        }
        part[g][x] = acc;
    }
    __syncthreads();

    if (tid < 64) {
        const float acc = bias[0] + part[0][tid] + part[1][tid] + part[2][tid] + part[3][tid];
        gate[tid] = 1.0f / (1.0f + expf(-acc));
    }
    __syncthreads();

    // ---- scale: 256 channels x 16 float4 columns, batch-4 MLP ----
    const int w4 = tid & 15;          // float4 column (constant per thread)
    const int c0 = tid >> 4;          // channel subgroup (0..15)
    const f32x4 g4 = ((const f32x4*)gate)[w4];   // 2-way LDS aliasing: free

    const f32x4* X4 = (const f32x4*)(X   + (size_t)b * CHWn + (size_t)h * Wn) + w4;
    f32x4*       O4 = (f32x4*)      (out + (size_t)b * CHWn + (size_t)h * Wn) + w4;

    #pragma unroll
    for (int k0 = 0; k0 < 16; k0 += 4) {
        f32x4 v0, v1, v2, v3;
        const size_t o0 = (size_t)((k0 + 0) * 16 + c0) * (HWn / 4);
        const size_t o1 = (size_t)((k0 + 1) * 16 + c0) * (HWn / 4);
        const size_t o2 = (size_t)((k0 + 2) * 16 + c0) * (HWn / 4);
        const size_t o3 = (size_t)((k0 + 3) * 16 + c0) * (HWn / 4);
        v0 = X4[o0];
        v1 = X4[o1];
        v2 = X4[o2];
        v3 = X4[o3];
        v0 *= g4; v1 *= g4; v2 *= g4; v3 *= g4;
        __builtin_nontemporal_store(v0, O4 + o0);
        __builtin_nontemporal_store(v1, O4 + o1);
        __builtin_nontemporal_store(v2, O4 + o2);
        __builtin_nontemporal_store(v3, O4 + o3);
    }
}

extern "C" void kernel_launch(void* const* d_in, const int* in_sizes, int n_in,
                              void* d_out, int out_size, void* d_ws, size_t ws_size,
                              hipStream_t stream) {
    const float* X      = (const float*)d_in[0];
    const float* conv_w = (const float*)d_in[1];
    const float* conv_b = (const float*)d_in[2];
    float* out = (float*)d_out;

    // workspace: maxp | avgp  (each B*H*W floats = 512 KiB)
    float* maxp = (float*)d_ws;
    float* avgp = maxp + Bn * HWn;

    // 1) pooling: one block per (b, h) row
    pool_kernel<<<Bn * Hn, 256, 0, stream>>>(X, maxp, avgp);

    // 2) conv + sigmoid + broadcast multiply, fused
    conv_scale_kernel<<<Bn * Hn, 256, 0, stream>>>(X, maxp, avgp, conv_w, conv_b, out);
}

// Round 8
// 68.304 us; speedup vs baseline: 3.8391x; 1.0143x over previous
//
#include <hip/hip_runtime.h>
#include <math.h>

#define Bn 32
#define Cn 256
#define Hn 64
#define Wn 64
#define HWn (Hn * Wn)          /* 4096 */
#define CHWn (Cn * HWn)        /* 1048576 */

typedef float f32x4 __attribute__((ext_vector_type(4)));

// ---------------------------------------------------------------------------
// Kernel 1: channel-wise max & mean pooling.
// One block per (b, h) row. 256 threads = 16 channel-groups x 16 float4 cols.
// Each thread reduces 16 channels for its float4 column, then LDS tree-reduce
// across the channel-group axis (strides 128..16 preserve the column index).
// Consecutive blocks = consecutive h rows of the same image, so co-scheduled
// blocks read adjacent 256B granules of each channel -> good DRAM page reuse.
// ---------------------------------------------------------------------------
__global__ __launch_bounds__(256) void pool_kernel(const float* __restrict__ X,
                                                   float* __restrict__ maxp,
                                                   float* __restrict__ avgp) {
    const int tid   = threadIdx.x;
    const int w4    = tid & 15;    // float4 column within the row (0..15)
    const int c_sub = tid >> 4;    // channel group (0..15)
    const int b     = blockIdx.x >> 6;
    const int h     = blockIdx.x & 63;

    const f32x4* Xb = (const f32x4*)(X + (size_t)b * CHWn + (size_t)h * Wn) + w4;

    f32x4 mx = { -INFINITY, -INFINITY, -INFINITY, -INFINITY };
    f32x4 sm = { 0.f, 0.f, 0.f, 0.f };
    #pragma unroll
    for (int k = 0; k < 16; ++k) {
        const int c = c_sub * 16 + k;
        f32x4 v = Xb[(size_t)c * (HWn / 4)];
        mx.x = fmaxf(mx.x, v.x); mx.y = fmaxf(mx.y, v.y);
        mx.z = fmaxf(mx.z, v.z); mx.w = fmaxf(mx.w, v.w);
        sm += v;
    }

    __shared__ f32x4 smax[256];
    __shared__ f32x4 ssum[256];
    smax[tid] = mx;
    ssum[tid] = sm;
    __syncthreads();

    #pragma unroll
    for (int s = 128; s >= 16; s >>= 1) {
        if (tid < s) {
            f32x4 a = smax[tid], c = smax[tid + s];
            a.x = fmaxf(a.x, c.x); a.y = fmaxf(a.y, c.y);
            a.z = fmaxf(a.z, c.z); a.w = fmaxf(a.w, c.w);
            smax[tid] = a;
            ssum[tid] += ssum[tid + s];
        }
        __syncthreads();
    }

    if (tid < 16) {
        f32x4 m = smax[tid];
        f32x4 a = ssum[tid] * (1.0f / (float)Cn);
        const int o = b * (HWn / 4) + h * 16 + tid;
        ((f32x4*)maxp)[o] = m;
        ((f32x4*)avgp)[o] = a;
    }
}

// ---------------------------------------------------------------------------
// Kernel 2 (fused): 7x7 conv + bias + sigmoid -> gate (LDS), then
// out[b,c,h,:] = gate[h,:] * X[b,c,h,:] for all 256 channels.
// One block per (b, h) row; conv split across the 4 waves (rows g, g+4),
// partials combined in LDS. Scale loop: simple form (compiler pipelines it;
// explicit batch-4 measured neutral). nt-store on out (never re-read).
// ---------------------------------------------------------------------------
__global__ __launch_bounds__(256) void conv_scale_kernel(const float* __restrict__ X,
                                                         const float* __restrict__ maxp,
                                                         const float* __restrict__ avgp,
                                                         const float* __restrict__ wgt,  // 98 (OIHW)
                                                         const float* __restrict__ bias, // 1
                                                         float* __restrict__ out) {
    __shared__ float ws[98];
    __shared__ float part[4][64];
    __shared__ float gate[64];

    const int tid = threadIdx.x;
    const int b = blockIdx.x >> 6;
    const int h = blockIdx.x & 63;

    if (tid < 98) ws[tid] = wgt[tid];
    __syncthreads();

    // conv partials: wave g handles kernel rows {g, g+4}; pixel x = tid & 63
    {
        const int x = tid & 63;
        const int g = tid >> 6;
        const float* mp = maxp + b * HWn;
        const float* ap = avgp + b * HWn;
        float acc = 0.f;
        #pragma unroll
        for (int ii = 0; ii < 2; ++ii) {
            const int i = g + ii * 4;          // rows 0..6 (g=3,ii=1 -> 7: skip)
            if (i > 6) continue;
            const int yy = h + i - 3;
            if (yy < 0 || yy >= Hn) continue;
            #pragma unroll
            for (int j = 0; j < 7; ++j) {
                const int xx = x + j - 3;
                if (xx < 0 || xx >= Wn) continue;
                const int o = yy * Wn + xx;
                acc += ws[i * 7 + j] * mp[o] + ws[49 + i * 7 + j] * ap[o];
            }
        }
        part[g][x] = acc;
    }
    __syncthreads();

    if (tid < 64) {
        const float acc = bias[0] + part[0][tid] + part[1][tid] + part[2][tid] + part[3][tid];
        gate[tid] = 1.0f / (1.0f + expf(-acc));
    }
    __syncthreads();

    // ---- scale: 256 channels x 16 float4 columns = 4096 float4 per block ----
    const int w4 = tid & 15;          // float4 column (constant per thread)
    const int c0 = tid >> 4;          // channel subgroup (0..15)
    const f32x4 g4 = ((const f32x4*)gate)[w4];   // 2-way LDS aliasing: free

    const f32x4* X4 = (const f32x4*)(X   + (size_t)b * CHWn + (size_t)h * Wn) + w4;
    f32x4*       O4 = (f32x4*)      (out + (size_t)b * CHWn + (size_t)h * Wn) + w4;

    #pragma unroll
    for (int k = 0; k < 16; ++k) {
        const int c = k * 16 + c0;
        const size_t off = (size_t)c * (HWn / 4);
        f32x4 v = X4[off];
        v *= g4;
        __builtin_nontemporal_store(v, O4 + off);
    }
}

extern "C" void kernel_launch(void* const* d_in, const int* in_sizes, int n_in,
                              void* d_out, int out_size, void* d_ws, size_t ws_size,
                              hipStream_t stream) {
    const float* X      = (const float*)d_in[0];
    const float* conv_w = (const float*)d_in[1];
    const float* conv_b = (const float*)d_in[2];
    float* out = (float*)d_out;

    // workspace: maxp | avgp  (each B*H*W floats = 512 KiB)
    float* maxp = (float*)d_ws;
    float* avgp = maxp + Bn * HWn;

    // 1) pooling: one block per (b, h) row
    pool_kernel<<<Bn * Hn, 256, 0, stream>>>(X, maxp, avgp);

    // 2) conv + sigmoid + broadcast multiply, fused
    conv_scale_kernel<<<Bn * Hn, 256, 0, stream>>>(X, maxp, avgp, conv_w, conv_b, out);
}